// Round 2
// baseline (617.139 us; speedup 1.0000x reference)
//
#include <hip/hip_runtime.h>
#include <math.h>

#define B_   8
#define N_   6
#define D_   41
#define C_   64
#define FH_  16
#define FW_  44
#define HW_  (FH_*FW_)          // 704
#define CHW_ ((D_+C_)*FH_*FW_)  // 73920
#define NPIX (B_*N_*FH_*FW_)    // 33792
#define NPT  (NPIX*D_)          // 1385472
#define NXV  200
#define NYV  200
#define NVOX (B_*NXV*NYV)       // 320000
#define NVOXP 320512            // 313*1024 (padded for int4 scan)
#define NSCANB 313

// exact-rounding helpers: prevent FMA contraction / reassociation
__device__ __forceinline__ float mul_(float a, float b){ return __fmul_rn(a,b); }
__device__ __forceinline__ float add_(float a, float b){ return __fadd_rn(a,b); }
__device__ __forceinline__ float sub_(float a, float b){ return __fsub_rn(a,b); }

// 3x3 inverse mirroring LAPACK getrf (partial pivot) + getrs (divisions kept)
__device__ void inv3(const float* A, float* X){
  float U[3][3];
  float L[3][3] = {{1.f,0.f,0.f},{0.f,1.f,0.f},{0.f,0.f,1.f}};
  int p[3] = {0,1,2};
  #pragma unroll
  for (int i=0;i<3;i++)
    #pragma unroll
    for (int j=0;j<3;j++) U[i][j] = A[i*3+j];
  #pragma unroll
  for (int k=0;k<3;k++){
    int pr = k; float mx = fabsf(U[k][k]);
    #pragma unroll
    for (int r=0;r<3;r++){
      if (r > k){ float v = fabsf(U[r][k]); if (v > mx){ mx = v; pr = r; } }
    }
    if (pr != k){
      #pragma unroll
      for (int j=0;j<3;j++){ float t=U[k][j]; U[k][j]=U[pr][j]; U[pr][j]=t; }
      #pragma unroll
      for (int j=0;j<3;j++){ if (j<k){ float t=L[k][j]; L[k][j]=L[pr][j]; L[pr][j]=t; } }
      int t=p[k]; p[k]=p[pr]; p[pr]=t;
    }
    #pragma unroll
    for (int r=0;r<3;r++){
      if (r > k){
        float m = __fdiv_rn(U[r][k], U[k][k]);
        L[r][k] = m;
        #pragma unroll
        for (int j=0;j<3;j++){ if (j>k) U[r][j] = sub_(U[r][j], mul_(m, U[k][j])); }
      }
    }
  }
  #pragma unroll
  for (int col=0; col<3; col++){
    float y[3];
    #pragma unroll
    for (int i=0;i<3;i++) y[i] = (p[i]==col) ? 1.f : 0.f;
    #pragma unroll
    for (int i=1;i<3;i++)
      #pragma unroll
      for (int j=0;j<3;j++){ if (j<i) y[i] = sub_(y[i], mul_(L[i][j], y[j])); }
    float x[3];
    #pragma unroll
    for (int i=2;i>=0;i--){
      float t = y[i];
      #pragma unroll
      for (int j=0;j<3;j++){ if (j>i) t = sub_(t, mul_(U[i][j], x[j])); }
      x[i] = __fdiv_rn(t, U[i][i]);
    }
    X[0*3+col]=x[0]; X[1*3+col]=x[1]; X[2*3+col]=x[2];
  }
}

// per-(b,n) params: invPost(9), M = rots@inv(intrins) (9), post_trans(3), trans(3)
__global__ void lss_prep(const float* __restrict__ rots, const float* __restrict__ trans,
                         const float* __restrict__ intrins, const float* __restrict__ post_rots,
                         const float* __restrict__ post_trans, float* __restrict__ cam){
  int t = threadIdx.x;
  if (t >= B_*N_) return;
  float invK[9], invP[9];
  inv3(intrins + t*9, invK);
  inv3(post_rots + t*9, invP);
  const float* R = rots + t*9;
  float M[9];
  #pragma unroll
  for (int i=0;i<3;i++)
    #pragma unroll
    for (int j=0;j<3;j++){
      float s = mul_(R[i*3+0], invK[0*3+j]);
      s = add_(s, mul_(R[i*3+1], invK[1*3+j]));
      s = add_(s, mul_(R[i*3+2], invK[2*3+j]));
      M[i*3+j] = s;
    }
  float* o = cam + t*24;
  #pragma unroll
  for (int i=0;i<9;i++) o[i] = invP[i];
  #pragma unroll
  for (int i=0;i<9;i++) o[9+i] = M[i];
  o[18]=post_trans[t*3+0]; o[19]=post_trans[t*3+1]; o[20]=post_trans[t*3+2];
  o[21]=trans[t*3+0];      o[22]=trans[t*3+1];      o[23]=trans[t*3+2];
}

// exact same rounding chain as the R1 (passing) kernel
__device__ __forceinline__ int point_voxel(const float* __restrict__ cam, int pix, int d){
  int w = pix % FW_; int t = pix / FW_;
  int h = t % FH_;   int bn = t / FH_;
  const float* cp = cam + bn*24;
  float u = mul_((float)w, 703.0f/43.0f);
  float v = mul_((float)h, 17.0f);
  float p0 = sub_(u, cp[18]);
  float p1 = sub_(v, cp[19]);
  float a0 = add_(mul_(cp[0],p0), mul_(cp[1],p1));
  float a1 = add_(mul_(cp[3],p0), mul_(cp[4],p1));
  float a2 = add_(mul_(cp[6],p0), mul_(cp[7],p1));
  float dd = add_(4.0f, (float)d);
  float p2 = sub_(dd, cp[20]);
  float r0 = add_(a0, mul_(cp[2],p2));
  float r1 = add_(a1, mul_(cp[5],p2));
  float r2 = add_(a2, mul_(cp[8],p2));
  float q0 = mul_(r0, r2), q1 = mul_(r1, r2), q2 = r2;
  float g0 = add_(add_(add_(mul_(cp[9], q0), mul_(cp[10],q1)), mul_(cp[11],q2)), cp[21]);
  float g1 = add_(add_(add_(mul_(cp[12],q0), mul_(cp[13],q1)), mul_(cp[14],q2)), cp[22]);
  float g2 = add_(add_(add_(mul_(cp[15],q0), mul_(cp[16],q1)), mul_(cp[17],q2)), cp[23]);
  float bxq = mul_(sub_(g0, -50.0f), 2.0f);
  float byq = mul_(sub_(g1, -50.0f), 2.0f);
  float bzq = __fdiv_rn(sub_(g2, -10.0f), 20.0f);
  int gx=(int)bxq, gy=(int)byq, gz=(int)bzq;
  int b = bn / N_;
  if ((gx>=0)&(gx<NXV)&(gy>=0)&(gy<NYV)&(gz==0))
    return (b*NXV + gx)*NYV + gy;
  return -1;
}

// per-pixel wave: softmax over D logits -> dprobA; channel transpose -> featT[pix][c]
__global__ __launch_bounds__(256) void lss_featprep(const float* __restrict__ feat,
    float* __restrict__ featT, float* __restrict__ dprobA){
  int wave = threadIdx.x >> 6, lane = threadIdx.x & 63;
  int pix = blockIdx.x*4 + wave;
  if (pix >= NPIX) return;
  int w = pix % FW_; int t = pix / FW_;
  int h = t % FH_;   int bn = t / FH_;
  const float* fb = feat + (size_t)bn*CHW_ + h*FW_ + w;
  float logit = (lane < D_) ? fb[(size_t)lane*HW_] : -INFINITY;
  float mx = logit;
  #pragma unroll
  for (int o=32;o;o>>=1) mx = fmaxf(mx, __shfl_xor(mx,o));
  float e = (lane < D_) ? expf(logit - mx) : 0.f;
  float ssum = e;
  #pragma unroll
  for (int o=32;o;o>>=1) ssum += __shfl_xor(ssum,o);
  if (lane < D_) dprobA[pix*D_ + lane] = e / ssum;
  featT[(size_t)pix*C_ + lane] = fb[(size_t)(D_+lane)*HW_];
}

__global__ __launch_bounds__(256) void lss_count(const float* __restrict__ cam,
                                                 int* __restrict__ cnt){
  int tid = blockIdx.x*256 + threadIdx.x;
  if (tid >= NPT) return;
  int pix = tid / D_, d = tid - pix*D_;
  int v = point_voxel(cam, pix, d);
  if (v >= 0) atomicAdd(&cnt[v], 1);
}

// ---- 3-kernel exclusive scan over NVOXP (padded with zeros) ----
__global__ __launch_bounds__(256) void scan_sums(const int* __restrict__ cnt,
                                                 int* __restrict__ bsum){
  int b = blockIdx.x, t = threadIdx.x;
  int4 v = ((const int4*)(cnt + b*1024))[t];
  int s = v.x+v.y+v.z+v.w;
  #pragma unroll
  for (int o=32;o;o>>=1) s += __shfl_xor(s,o);
  __shared__ int ws[4];
  if ((t&63)==0) ws[t>>6] = s;
  __syncthreads();
  if (t==0) bsum[b] = ws[0]+ws[1]+ws[2]+ws[3];
}

__global__ __launch_bounds__(512) void scan_mid(const int* __restrict__ bsum,
                                                int* __restrict__ ebsum){
  __shared__ int s[512];
  int t = threadIdx.x;
  int v = (t < NSCANB) ? bsum[t] : 0;
  s[t] = v; __syncthreads();
  for (int o=1;o<512;o<<=1){
    int u = (t>=o) ? s[t-o] : 0;
    __syncthreads();
    s[t] += u;
    __syncthreads();
  }
  if (t < NSCANB) ebsum[t] = s[t] - v;
}

__global__ __launch_bounds__(256) void scan_final(const int* __restrict__ cnt,
    const int* __restrict__ ebsum, int* __restrict__ offs){
  int b = blockIdx.x, t = threadIdx.x, lane = t&63, w = t>>6;
  int4 v = ((const int4*)(cnt + b*1024))[t];
  int s = v.x+v.y+v.z+v.w;
  int incl = s;
  #pragma unroll
  for (int o=1;o<64;o<<=1){ int u = __shfl_up(incl,o); if (lane>=o) incl += u; }
  __shared__ int ws[4];
  if (lane==63) ws[w] = incl;
  __syncthreads();
  int base = ebsum[b];
  #pragma unroll
  for (int i=0;i<3;i++){ if (i < w) base += ws[i]; }
  int excl = base + incl - s;
  int4 o4; o4.x = excl; o4.y = excl+v.x; o4.z = o4.y+v.y; o4.w = o4.z+v.z;
  ((int4*)(offs + b*1024))[t] = o4;
}

__global__ __launch_bounds__(256) void lss_fill(const float* __restrict__ cam,
    const float* __restrict__ dprobA, int* __restrict__ cur, uint2* __restrict__ rec){
  int tid = blockIdx.x*256 + threadIdx.x;
  if (tid >= NPT) return;
  int pix = tid / D_, d = tid - pix*D_;
  int v = point_voxel(cam, pix, d);
  if (v >= 0){
    int pos = atomicAdd(&cur[v], 1);
    uint2 r; r.x = (unsigned)pix; r.y = __float_as_uint(dprobA[tid]);
    rec[pos] = r;
  }
}

// one wave per voxel run of 16; lane = channel; fused transpose-write to out[b][c][x][y]
__global__ __launch_bounds__(256) void lss_gather(const float* __restrict__ featT,
    const uint2* __restrict__ rec, const int* __restrict__ offs,
    const int* __restrict__ cnt, float* __restrict__ out){
  __shared__ float lds[64][65];
  int bid = blockIdx.x;
  int tile = bid & 3;
  int x    = (bid >> 2) % NXV;
  int b    = bid / (NXV*4);
  int y0   = tile*64;
  int lane = threadIdx.x & 63, wv = threadIdx.x >> 6;
  for (int i=0;i<16;i++){
    int yl = wv*16 + i;
    int y  = y0 + yl;
    float acc = 0.f;
    if (y < NYV){
      int v  = (b*NXV + x)*NYV + y;
      int st = offs[v], c = cnt[v];
      if (c > 0){
        uint2 r = rec[st];
        for (int j=0;j<c;j++){
          uint2 rn = (j+1 < c) ? rec[st+j+1] : r;   // prefetch next
          acc = fmaf(__uint_as_float(r.y), featT[(size_t)r.x*C_ + lane], acc);
          r = rn;
        }
      }
    }
    lds[yl][lane] = acc;
  }
  __syncthreads();
  int y = y0 + lane;
  if (y < NYV){
    #pragma unroll
    for (int cc=wv; cc<64; cc+=4)
      out[(((size_t)(b*C_ + cc))*NXV + x)*NYV + y] = lds[lane][cc];
  }
}

// R1 fallback: direct atomics into out (only used if ws is unexpectedly small)
__global__ __launch_bounds__(256) void lss_scatter_fb(const float* __restrict__ feat,
    const float* __restrict__ cam, float* __restrict__ pooled){
  int wave = threadIdx.x >> 6, lane = threadIdx.x & 63;
  int pix = blockIdx.x*4 + wave;
  if (pix >= NPIX) return;
  int w = pix % FW_; int t = pix / FW_;
  int h = t % FH_;   t /= FH_;
  int n = t % N_;    int b = t / N_;
  const float* cp = cam + (b*N_+n)*24;
  const float* fb = feat + (size_t)(b*N_+n)*CHW_ + h*FW_ + w;
  float logit = (lane < D_) ? fb[(size_t)lane*HW_] : -INFINITY;
  float mx = logit;
  #pragma unroll
  for (int o=32;o;o>>=1) mx = fmaxf(mx, __shfl_xor(mx,o));
  float e = (lane < D_) ? expf(logit - mx) : 0.f;
  float ssum = e;
  #pragma unroll
  for (int o=32;o;o>>=1) ssum += __shfl_xor(ssum,o);
  float dprob = e / ssum;
  float fc = fb[(size_t)(D_+lane)*HW_];
  for (int d=0; d<D_; d++){
    int pv = point_voxel(cam, pix, d);
    if (pv >= 0){
      int gx = (pv / NYV) % NXV, gy = pv % NYV;
      float dp  = __shfl(dprob, d);
      atomicAdd(&pooled[(((size_t)b*C_ + lane)*NXV + gx)*NYV + gy], mul_(dp, fc));
    }
  }
}

extern "C" void kernel_launch(void* const* d_in, const int* in_sizes, int n_in,
                              void* d_out, int out_size, void* d_ws, size_t ws_size,
                              hipStream_t stream) {
  const float* feat       = (const float*)d_in[0];
  const float* rots       = (const float*)d_in[1];
  const float* trans      = (const float*)d_in[2];
  const float* intrins    = (const float*)d_in[3];
  const float* post_rots  = (const float*)d_in[4];
  const float* post_trans = (const float*)d_in[5];
  float* out = (float*)d_out;

  // ws layout (all 256B aligned)
  char* p = (char*)d_ws;
  float* cam    = (float*)p;                 p += 48*24*4;            // 4.6 KB
  float* featT  = (float*)p;                 p += (size_t)NPIX*C_*4;  // 8.65 MB
  float* dprobA = (float*)p;                 p += (size_t)NPT*4;      // 5.54 MB
  int*   cnt    = (int*)p;                   p += (size_t)NVOXP*4;    // 1.28 MB
  int*   offs   = (int*)p;                   p += (size_t)NVOXP*4;
  int*   cur    = (int*)p;                   p += (size_t)NVOXP*4;
  int*   bsum   = (int*)p;                   p += 1280;
  int*   ebsum  = (int*)p;                   p += 1280;
  uint2* rec    = (uint2*)p;                 p += (size_t)NPT*8;      // 11.1 MB
  size_t need = (size_t)(p - (char*)d_ws);

  if (ws_size < need){
    // fallback: direct atomics (slow, correct); needs only cam
    hipMemsetAsync(d_out, 0, (size_t)out_size*sizeof(float), stream);
    lss_prep<<<1, 64, 0, stream>>>(rots, trans, intrins, post_rots, post_trans, (float*)d_ws);
    lss_scatter_fb<<<NPIX/4, 256, 0, stream>>>(feat, (float*)d_ws, out);
    return;
  }

  hipMemsetAsync(cnt, 0, (size_t)NVOXP*4, stream);
  lss_prep<<<1, 64, 0, stream>>>(rots, trans, intrins, post_rots, post_trans, cam);
  lss_featprep<<<NPIX/4, 256, 0, stream>>>(feat, featT, dprobA);
  lss_count<<<NPT/256, 256, 0, stream>>>(cam, cnt);
  scan_sums<<<NSCANB, 256, 0, stream>>>(cnt, bsum);
  scan_mid<<<1, 512, 0, stream>>>(bsum, ebsum);
  scan_final<<<NSCANB, 256, 0, stream>>>(cnt, ebsum, offs);
  hipMemcpyAsync(cur, offs, (size_t)NVOXP*4, hipMemcpyDeviceToDevice, stream);
  lss_fill<<<NPT/256, 256, 0, stream>>>(cam, dprobA, cur, rec);
  lss_gather<<<B_*NXV*4, 256, 0, stream>>>(featT, rec, offs, cnt, out);
}

// Round 3
// 615.612 us; speedup vs baseline: 1.0025x; 1.0025x over previous
//
#include <hip/hip_runtime.h>
#include <math.h>

#define B_   8
#define N_   6
#define D_   41
#define C_   64
#define FH_  16
#define FW_  44
#define HW_  (FH_*FW_)          // 704
#define CHW_ ((D_+C_)*FH_*FW_)  // 73920
#define NPIX (B_*N_*FH_*FW_)    // 33792
#define NPT  (NPIX*D_)          // 1385472
#define NXV  200
#define NYV  200
#define NVOX (B_*NXV*NYV)       // 320000
#define NVOXP 320512            // 313*1024 (padded for int4 scan)
#define NSCANB 313

// exact-rounding helpers: prevent FMA contraction / reassociation
__device__ __forceinline__ float mul_(float a, float b){ return __fmul_rn(a,b); }
__device__ __forceinline__ float add_(float a, float b){ return __fadd_rn(a,b); }
__device__ __forceinline__ float sub_(float a, float b){ return __fsub_rn(a,b); }

// 3x3 inverse mirroring LAPACK getrf (partial pivot) + getrs (divisions kept)
__device__ void inv3(const float* A, float* X){
  float U[3][3];
  float L[3][3] = {{1.f,0.f,0.f},{0.f,1.f,0.f},{0.f,0.f,1.f}};
  int p[3] = {0,1,2};
  #pragma unroll
  for (int i=0;i<3;i++)
    #pragma unroll
    for (int j=0;j<3;j++) U[i][j] = A[i*3+j];
  #pragma unroll
  for (int k=0;k<3;k++){
    int pr = k; float mx = fabsf(U[k][k]);
    #pragma unroll
    for (int r=0;r<3;r++){
      if (r > k){ float v = fabsf(U[r][k]); if (v > mx){ mx = v; pr = r; } }
    }
    if (pr != k){
      #pragma unroll
      for (int j=0;j<3;j++){ float t=U[k][j]; U[k][j]=U[pr][j]; U[pr][j]=t; }
      #pragma unroll
      for (int j=0;j<3;j++){ if (j<k){ float t=L[k][j]; L[k][j]=L[pr][j]; L[pr][j]=t; } }
      int t=p[k]; p[k]=p[pr]; p[pr]=t;
    }
    #pragma unroll
    for (int r=0;r<3;r++){
      if (r > k){
        float m = __fdiv_rn(U[r][k], U[k][k]);
        L[r][k] = m;
        #pragma unroll
        for (int j=0;j<3;j++){ if (j>k) U[r][j] = sub_(U[r][j], mul_(m, U[k][j])); }
      }
    }
  }
  #pragma unroll
  for (int col=0; col<3; col++){
    float y[3];
    #pragma unroll
    for (int i=0;i<3;i++) y[i] = (p[i]==col) ? 1.f : 0.f;
    #pragma unroll
    for (int i=1;i<3;i++)
      #pragma unroll
      for (int j=0;j<3;j++){ if (j<i) y[i] = sub_(y[i], mul_(L[i][j], y[j])); }
    float x[3];
    #pragma unroll
    for (int i=2;i>=0;i--){
      float t = y[i];
      #pragma unroll
      for (int j=0;j<3;j++){ if (j>i) t = sub_(t, mul_(U[i][j], x[j])); }
      x[i] = __fdiv_rn(t, U[i][i]);
    }
    X[0*3+col]=x[0]; X[1*3+col]=x[1]; X[2*3+col]=x[2];
  }
}

// per-(b,n) params: invPost(9), M = rots@inv(intrins) (9), post_trans(3), trans(3)
__global__ void lss_prep(const float* __restrict__ rots, const float* __restrict__ trans,
                         const float* __restrict__ intrins, const float* __restrict__ post_rots,
                         const float* __restrict__ post_trans, float* __restrict__ cam){
  int t = threadIdx.x;
  if (t >= B_*N_) return;
  float invK[9], invP[9];
  inv3(intrins + t*9, invK);
  inv3(post_rots + t*9, invP);
  const float* R = rots + t*9;
  float M[9];
  #pragma unroll
  for (int i=0;i<3;i++)
    #pragma unroll
    for (int j=0;j<3;j++){
      float s = mul_(R[i*3+0], invK[0*3+j]);
      s = add_(s, mul_(R[i*3+1], invK[1*3+j]));
      s = add_(s, mul_(R[i*3+2], invK[2*3+j]));
      M[i*3+j] = s;
    }
  float* o = cam + t*24;
  #pragma unroll
  for (int i=0;i<9;i++) o[i] = invP[i];
  #pragma unroll
  for (int i=0;i<9;i++) o[9+i] = M[i];
  o[18]=post_trans[t*3+0]; o[19]=post_trans[t*3+1]; o[20]=post_trans[t*3+2];
  o[21]=trans[t*3+0];      o[22]=trans[t*3+1];      o[23]=trans[t*3+2];
}

// exact same rounding chain as the R1 (passing) kernel
__device__ __forceinline__ int point_voxel(const float* __restrict__ cam, int pix, int d){
  int w = pix % FW_; int t = pix / FW_;
  int h = t % FH_;   int bn = t / FH_;
  const float* cp = cam + bn*24;
  float u = mul_((float)w, 703.0f/43.0f);
  float v = mul_((float)h, 17.0f);
  float p0 = sub_(u, cp[18]);
  float p1 = sub_(v, cp[19]);
  float a0 = add_(mul_(cp[0],p0), mul_(cp[1],p1));
  float a1 = add_(mul_(cp[3],p0), mul_(cp[4],p1));
  float a2 = add_(mul_(cp[6],p0), mul_(cp[7],p1));
  float dd = add_(4.0f, (float)d);
  float p2 = sub_(dd, cp[20]);
  float r0 = add_(a0, mul_(cp[2],p2));
  float r1 = add_(a1, mul_(cp[5],p2));
  float r2 = add_(a2, mul_(cp[8],p2));
  float q0 = mul_(r0, r2), q1 = mul_(r1, r2), q2 = r2;
  float g0 = add_(add_(add_(mul_(cp[9], q0), mul_(cp[10],q1)), mul_(cp[11],q2)), cp[21]);
  float g1 = add_(add_(add_(mul_(cp[12],q0), mul_(cp[13],q1)), mul_(cp[14],q2)), cp[22]);
  float g2 = add_(add_(add_(mul_(cp[15],q0), mul_(cp[16],q1)), mul_(cp[17],q2)), cp[23]);
  float bxq = mul_(sub_(g0, -50.0f), 2.0f);
  float byq = mul_(sub_(g1, -50.0f), 2.0f);
  float bzq = __fdiv_rn(sub_(g2, -10.0f), 20.0f);
  int gx=(int)bxq, gy=(int)byq, gz=(int)bzq;
  int b = bn / N_;
  if ((gx>=0)&(gx<NXV)&(gy>=0)&(gy<NYV)&(gz==0))
    return (b*NXV + gx)*NYV + gy;
  return -1;
}

// per-pixel wave: softmax over D logits -> dprobA; channel transpose -> featT[pix][c]
__global__ __launch_bounds__(256) void lss_featprep(const float* __restrict__ feat,
    float* __restrict__ featT, float* __restrict__ dprobA){
  int wave = threadIdx.x >> 6, lane = threadIdx.x & 63;
  int pix = blockIdx.x*4 + wave;
  if (pix >= NPIX) return;
  int w = pix % FW_; int t = pix / FW_;
  int h = t % FH_;   int bn = t / FH_;
  const float* fb = feat + (size_t)bn*CHW_ + h*FW_ + w;
  float logit = (lane < D_) ? fb[(size_t)lane*HW_] : -INFINITY;
  float mx = logit;
  #pragma unroll
  for (int o=32;o;o>>=1) mx = fmaxf(mx, __shfl_xor(mx,o));
  float e = (lane < D_) ? expf(logit - mx) : 0.f;
  float ssum = e;
  #pragma unroll
  for (int o=32;o;o>>=1) ssum += __shfl_xor(ssum,o);
  if (lane < D_) dprobA[pix*D_ + lane] = e / ssum;
  featT[(size_t)pix*C_ + lane] = fb[(size_t)(D_+lane)*HW_];
}

__global__ __launch_bounds__(256) void lss_count(const float* __restrict__ cam,
                                                 int* __restrict__ cnt){
  int tid = blockIdx.x*256 + threadIdx.x;
  if (tid >= NPT) return;
  int pix = tid / D_, d = tid - pix*D_;
  int v = point_voxel(cam, pix, d);
  if (v >= 0) atomicAdd(&cnt[v], 1);
}

// ---- 3-kernel exclusive scan over NVOXP (padded with zeros) ----
__global__ __launch_bounds__(256) void scan_sums(const int* __restrict__ cnt,
                                                 int* __restrict__ bsum){
  int b = blockIdx.x, t = threadIdx.x;
  int4 v = ((const int4*)(cnt + b*1024))[t];
  int s = v.x+v.y+v.z+v.w;
  #pragma unroll
  for (int o=32;o;o>>=1) s += __shfl_xor(s,o);
  __shared__ int ws[4];
  if ((t&63)==0) ws[t>>6] = s;
  __syncthreads();
  if (t==0) bsum[b] = ws[0]+ws[1]+ws[2]+ws[3];
}

__global__ __launch_bounds__(512) void scan_mid(const int* __restrict__ bsum,
                                                int* __restrict__ ebsum){
  __shared__ int s[512];
  int t = threadIdx.x;
  int v = (t < NSCANB) ? bsum[t] : 0;
  s[t] = v; __syncthreads();
  for (int o=1;o<512;o<<=1){
    int u = (t>=o) ? s[t-o] : 0;
    __syncthreads();
    s[t] += u;
    __syncthreads();
  }
  if (t < NSCANB) ebsum[t] = s[t] - v;
}

__global__ __launch_bounds__(256) void scan_final(const int* __restrict__ cnt,
    const int* __restrict__ ebsum, int* __restrict__ offs){
  int b = blockIdx.x, t = threadIdx.x, lane = t&63, w = t>>6;
  int4 v = ((const int4*)(cnt + b*1024))[t];
  int s = v.x+v.y+v.z+v.w;
  int incl = s;
  #pragma unroll
  for (int o=1;o<64;o<<=1){ int u = __shfl_up(incl,o); if (lane>=o) incl += u; }
  __shared__ int ws[4];
  if (lane==63) ws[w] = incl;
  __syncthreads();
  int base = ebsum[b];
  #pragma unroll
  for (int i=0;i<3;i++){ if (i < w) base += ws[i]; }
  int excl = base + incl - s;
  int4 o4; o4.x = excl; o4.y = excl+v.x; o4.z = o4.y+v.y; o4.w = o4.z+v.z;
  ((int4*)(offs + b*1024))[t] = o4;
}

__global__ __launch_bounds__(256) void lss_fill(const float* __restrict__ cam,
    const float* __restrict__ dprobA, int* __restrict__ cur, uint2* __restrict__ rec){
  int tid = blockIdx.x*256 + threadIdx.x;
  if (tid >= NPT) return;
  int pix = tid / D_, d = tid - pix*D_;
  int v = point_voxel(cam, pix, d);
  if (v >= 0){
    int pos = atomicAdd(&cur[v], 1);
    uint2 r; r.x = (unsigned)pix; r.y = __float_as_uint(dprobA[tid]);
    rec[pos] = r;
  }
}

// one wave per voxel run of 16; lane = channel; fused transpose-write to out[b][c][x][y]
__global__ __launch_bounds__(256) void lss_gather(const float* __restrict__ featT,
    const uint2* __restrict__ rec, const int* __restrict__ offs,
    const int* __restrict__ cnt, float* __restrict__ out){
  __shared__ float lds[64][65];
  int bid = blockIdx.x;
  int tile = bid & 3;
  int x    = (bid >> 2) % NXV;
  int b    = bid / (NXV*4);
  int y0   = tile*64;
  int lane = threadIdx.x & 63, wv = threadIdx.x >> 6;
  for (int i=0;i<16;i++){
    int yl = wv*16 + i;
    int y  = y0 + yl;
    float acc = 0.f;
    if (y < NYV){
      int v  = (b*NXV + x)*NYV + y;
      int st = offs[v], c = cnt[v];
      if (c > 0){
        uint2 r = rec[st];
        for (int j=0;j<c;j++){
          uint2 rn = (j+1 < c) ? rec[st+j+1] : r;   // prefetch next
          acc = fmaf(__uint_as_float(r.y), featT[(size_t)r.x*C_ + lane], acc);
          r = rn;
        }
      }
    }
    lds[yl][lane] = acc;
  }
  __syncthreads();
  int y = y0 + lane;
  if (y < NYV){
    #pragma unroll
    for (int cc=wv; cc<64; cc+=4)
      out[(((size_t)(b*C_ + cc))*NXV + x)*NYV + y] = lds[lane][cc];
  }
}

// R1 fallback: direct atomics into out (only used if ws is unexpectedly small)
__global__ __launch_bounds__(256) void lss_scatter_fb(const float* __restrict__ feat,
    const float* __restrict__ cam, float* __restrict__ pooled){
  int wave = threadIdx.x >> 6, lane = threadIdx.x & 63;
  int pix = blockIdx.x*4 + wave;
  if (pix >= NPIX) return;
  int w = pix % FW_; int t = pix / FW_;
  int h = t % FH_;   t /= FH_;
  int n = t % N_;    int b = t / N_;
  const float* cp = cam + (b*N_+n)*24;
  const float* fb = feat + (size_t)(b*N_+n)*CHW_ + h*FW_ + w;
  float logit = (lane < D_) ? fb[(size_t)lane*HW_] : -INFINITY;
  float mx = logit;
  #pragma unroll
  for (int o=32;o;o>>=1) mx = fmaxf(mx, __shfl_xor(mx,o));
  float e = (lane < D_) ? expf(logit - mx) : 0.f;
  float ssum = e;
  #pragma unroll
  for (int o=32;o;o>>=1) ssum += __shfl_xor(ssum,o);
  float dprob = e / ssum;
  float fc = fb[(size_t)(D_+lane)*HW_];
  for (int d=0; d<D_; d++){
    int pv = point_voxel(cam, pix, d);
    if (pv >= 0){
      int gx = (pv / NYV) % NXV, gy = pv % NYV;
      float dp  = __shfl(dprob, d);
      atomicAdd(&pooled[(((size_t)b*C_ + lane)*NXV + gx)*NYV + gy], mul_(dp, fc));
    }
  }
}

extern "C" void kernel_launch(void* const* d_in, const int* in_sizes, int n_in,
                              void* d_out, int out_size, void* d_ws, size_t ws_size,
                              hipStream_t stream) {
  const float* feat       = (const float*)d_in[0];
  const float* rots       = (const float*)d_in[1];
  const float* trans      = (const float*)d_in[2];
  const float* intrins    = (const float*)d_in[3];
  const float* post_rots  = (const float*)d_in[4];
  const float* post_trans = (const float*)d_in[5];
  float* out = (float*)d_out;

  // ws layout (all 256B aligned)
  char* p = (char*)d_ws;
  float* cam    = (float*)p;                 p += 48*24*4;            // 4.6 KB
  float* featT  = (float*)p;                 p += (size_t)NPIX*C_*4;  // 8.65 MB
  float* dprobA = (float*)p;                 p += (size_t)NPT*4;      // 5.54 MB
  int*   cnt    = (int*)p;                   p += (size_t)NVOXP*4;    // 1.28 MB
  int*   offs   = (int*)p;                   p += (size_t)NVOXP*4;
  int*   cur    = (int*)p;                   p += (size_t)NVOXP*4;
  int*   bsum   = (int*)p;                   p += 1280;
  int*   ebsum  = (int*)p;                   p += 1280;
  uint2* rec    = (uint2*)p;                 p += (size_t)NPT*8;      // 11.1 MB
  size_t need = (size_t)(p - (char*)d_ws);

  if (ws_size < need){
    // fallback: direct atomics (slow, correct); needs only cam
    hipMemsetAsync(d_out, 0, (size_t)out_size*sizeof(float), stream);
    lss_prep<<<1, 64, 0, stream>>>(rots, trans, intrins, post_rots, post_trans, (float*)d_ws);
    lss_scatter_fb<<<NPIX/4, 256, 0, stream>>>(feat, (float*)d_ws, out);
    return;
  }

  hipMemsetAsync(cnt, 0, (size_t)NVOXP*4, stream);
  lss_prep<<<1, 64, 0, stream>>>(rots, trans, intrins, post_rots, post_trans, cam);
  lss_featprep<<<NPIX/4, 256, 0, stream>>>(feat, featT, dprobA);
  lss_count<<<NPT/256, 256, 0, stream>>>(cam, cnt);
  scan_sums<<<NSCANB, 256, 0, stream>>>(cnt, bsum);
  scan_mid<<<1, 512, 0, stream>>>(bsum, ebsum);
  scan_final<<<NSCANB, 256, 0, stream>>>(cnt, ebsum, offs);
  hipMemcpyAsync(cur, offs, (size_t)NVOXP*4, hipMemcpyDeviceToDevice, stream);
  lss_fill<<<NPT/256, 256, 0, stream>>>(cam, dprobA, cur, rec);
  lss_gather<<<B_*NXV*4, 256, 0, stream>>>(featT, rec, offs, cnt, out);
}